// Round 1
// baseline (243.811 us; speedup 1.0000x reference)
//
#include <hip/hip_runtime.h>

// IF (integrate-and-fire) SNN forward scan.
// x: [T*B, C, H, W] fp32 viewed as [T=8, slice=B*C*H*W]; out: spikes, same shape.
// Per element n (independent across n): mem=0.5*thr; for t: mem+=x[t][n];
// sp=(mem>=thr)?thr:0; mem-=sp; out[t][n]=sp.
// Memory-bound: 268 MB traffic -> ~43 us roofline at 6.3 TB/s.

constexpr int T_STEPS = 8;

__global__ __launch_bounds__(256) void if_fwd_kernel(
    const float4* __restrict__ x,
    const float* __restrict__ thresh,
    float4* __restrict__ out,
    int stride4)   // elements-per-timestep / 4
{
    int i = blockIdx.x * blockDim.x + threadIdx.x;
    if (i >= stride4) return;

    const float thr = thresh[0];          // wave-uniform -> scalar load

    // Prefetch all 8 timesteps: 8 independent global_load_dwordx4 in flight.
    float4 xt[T_STEPS];
#pragma unroll
    for (int t = 0; t < T_STEPS; ++t) {
        xt[t] = x[(size_t)t * stride4 + i];
    }

    float m0 = 0.5f * thr;
    float m1 = 0.5f * thr;
    float m2 = 0.5f * thr;
    float m3 = 0.5f * thr;

#pragma unroll
    for (int t = 0; t < T_STEPS; ++t) {
        m0 += xt[t].x;
        m1 += xt[t].y;
        m2 += xt[t].z;
        m3 += xt[t].w;
        float s0 = (m0 >= thr) ? thr : 0.0f;
        float s1 = (m1 >= thr) ? thr : 0.0f;
        float s2 = (m2 >= thr) ? thr : 0.0f;
        float s3 = (m3 >= thr) ? thr : 0.0f;
        m0 -= s0;
        m1 -= s1;
        m2 -= s2;
        m3 -= s3;
        out[(size_t)t * stride4 + i] = make_float4(s0, s1, s2, s3);
    }
}

extern "C" void kernel_launch(void* const* d_in, const int* in_sizes, int n_in,
                              void* d_out, int out_size, void* d_ws, size_t ws_size,
                              hipStream_t stream) {
    const float* x      = (const float*)d_in[0];   // [T*B, C, H, W] fp32
    const float* thresh = (const float*)d_in[1];   // scalar threshold (1 elem)
    float* out          = (float*)d_out;           // same shape as x

    const int total   = in_sizes[0];       // 33,554,432
    const int stride  = total / T_STEPS;   // 4,194,304 elems per timestep
    const int stride4 = stride / 4;        // 1,048,576 float4s per timestep

    dim3 block(256);
    dim3 grid((stride4 + block.x - 1) / block.x);
    if_fwd_kernel<<<grid, block, 0, stream>>>(
        (const float4*)x, thresh, (float4*)out, stride4);
}

// Round 2
// 233.767 us; speedup vs baseline: 1.0430x; 1.0430x over previous
//
#include <hip/hip_runtime.h>

// IF (integrate-and-fire) SNN forward scan.
// x: [T*B, C, H, W] fp32 viewed as [T=8, slice=4,194,304 floats]; out same shape.
// Per element n: mem=0.5*thr; for t: mem+=x[t][n]; sp=(mem>=thr)?thr:0; mem-=sp.
//
// R1: float4, 1 per slice per thread -> 90 us, eff BW 3.0 TB/s (FETCH 64 MiB,
//     WRITE 132 MiB, VALUBusy 3%). Not BW-saturated -> burst-length + LLC
//     write-pollution theory.
// R2: ILP=2 float4 per slice (2 KiB/wave bursts, 16 loads in flight) +
//     nontemporal stores (don't evict restore-resident input from L3).

typedef float f4 __attribute__((ext_vector_type(4)));

constexpr int T_STEPS = 8;
constexpr int ILP = 2;          // float4s per slice per thread
constexpr int BLOCK = 256;

__global__ __launch_bounds__(BLOCK) void if_fwd_kernel(
    const f4* __restrict__ x,
    const float* __restrict__ thresh,
    f4* __restrict__ out,
    int stride4)   // float4s per timestep slice
{
    const int base = blockIdx.x * (BLOCK * ILP) + threadIdx.x;
    const float thr = thresh[0];          // wave-uniform -> scalar load

    // Prefetch all T*ILP = 16 loads; each wave covers 2 contiguous KiB per
    // slice (lanes coalesced, j-offset = +1 KiB).
    f4 xt[T_STEPS][ILP];
#pragma unroll
    for (int t = 0; t < T_STEPS; ++t) {
        const f4* p = x + (size_t)t * stride4 + base;
#pragma unroll
        for (int j = 0; j < ILP; ++j) {
            xt[t][j] = p[j * BLOCK];
        }
    }

    const float h = 0.5f * thr;
    f4 m[ILP];
#pragma unroll
    for (int j = 0; j < ILP; ++j) {
        m[j] = (f4){h, h, h, h};
    }

#pragma unroll
    for (int t = 0; t < T_STEPS; ++t) {
        f4* po = out + (size_t)t * stride4 + base;
#pragma unroll
        for (int j = 0; j < ILP; ++j) {
            m[j] += xt[t][j];
            f4 s;
#pragma unroll
            for (int k = 0; k < 4; ++k) {
                s[k] = (m[j][k] >= thr) ? thr : 0.0f;
            }
            m[j] -= s;
            // Nontemporal: output is single-touch; keep it from sweeping the
            // 256 MiB LLC and evicting the (restore-resident) input.
            __builtin_nontemporal_store(s, po + j * BLOCK);
        }
    }
}

extern "C" void kernel_launch(void* const* d_in, const int* in_sizes, int n_in,
                              void* d_out, int out_size, void* d_ws, size_t ws_size,
                              hipStream_t stream) {
    const float* x      = (const float*)d_in[0];   // [T*B, C, H, W] fp32
    const float* thresh = (const float*)d_in[1];   // scalar threshold (1 elem)
    float* out          = (float*)d_out;

    const int total   = in_sizes[0];       // 33,554,432
    const int stride  = total / T_STEPS;   // 4,194,304 elems per slice
    const int stride4 = stride / 4;        // 1,048,576 float4s per slice

    const int per_block = BLOCK * ILP;     // 512 float4s per block per slice
    dim3 block(BLOCK);
    dim3 grid((stride4 + per_block - 1) / per_block);   // 2048 blocks
    if_fwd_kernel<<<grid, block, 0, stream>>>(
        (const f4*)x, thresh, (f4*)out, stride4);
}